// Round 5
// baseline (468.708 us; speedup 1.0000x reference)
//
#include <hip/hip_runtime.h>
#include <hip/hip_bf16.h>
#include <math.h>

// ---------------------------------------------------------------------------
// 2-layer GCN on MI355X.
//   CSR build (hist -> wave-scan -> scatter)
//   xw1 = x @ W1    LDS-free streaming split-bf16 MFMA (frags direct from L1/L2)
//   h1  = relu(sym-norm-agg(xw1) + b1)   bf16 gather, 4-deep unroll
//   hw2 = h1 @ W2   LDS-free streaming bf16 MFMA, OUT=bf16
//   out = softmax(sym-norm-agg(hw2) + b2)  bf16 gather, 4-deep unroll
// ---------------------------------------------------------------------------

#define N_NODES 50000
#define N_EDGES 800000
#define D_IN    512
#define D_HID   256
#define D_OUT   64

#define OFF_COUNTER 0
#define OFF_DEG     256
#define OFF_DINV    (OFF_DEG + 200704)
#define OFF_OFFS    (OFF_DINV + 200704)
#define OFF_CURSOR  (OFF_OFFS + 200704)
#define OFF_CSR     (OFF_CURSOR + 200704)
#define OFF_XW1     (OFF_CSR + 3200000)     // xw1 bf16 25.6MB; later hw2 bf16 6.4MB
#define OFF_H1      (OFF_XW1 + 51200000)    // h1 bf16 25.6MB
// W1 hi/lo split inside the h1 region (dead before agg1 writes h1)
#define OFF_BHT     OFF_H1
#define OFF_BLT     (OFF_H1 + 524288)
#define OFF_W2T     (OFF_H1 + 25600000)     // W2T bf16 32KB (after h1's 25.6MB)
// total ~105 MB

typedef __attribute__((ext_vector_type(8))) short bf16x8;
typedef __attribute__((ext_vector_type(4))) float f32x4;

// round-to-nearest-even fp32 -> bf16 bits
__device__ __forceinline__ unsigned int f2bf(float v) {
    unsigned int u = __float_as_uint(v);
    return (u + 0x7FFFu + ((u >> 16) & 1u)) >> 16;
}
__device__ __forceinline__ float bf2f(unsigned int b) { return __uint_as_float(b << 16); }

// 8 fp32 -> hi/lo bf16x8 fragments
__device__ __forceinline__ void cvt8(float4 f0, float4 f1, bf16x8* hi, bf16x8* lo) {
    float v[8] = {f0.x, f0.y, f0.z, f0.w, f1.x, f1.y, f1.z, f1.w};
    unsigned int hu[8], lu[8];
    #pragma unroll
    for (int e = 0; e < 8; ++e) {
        hu[e] = f2bf(v[e]);
        float hf = __uint_as_float(hu[e] << 16);
        lu[e] = f2bf(v[e] - hf);
    }
    uint4 H = make_uint4(hu[0] | (hu[1] << 16), hu[2] | (hu[3] << 16),
                         hu[4] | (hu[5] << 16), hu[6] | (hu[7] << 16));
    uint4 L = make_uint4(lu[0] | (lu[1] << 16), lu[2] | (lu[3] << 16),
                         lu[4] | (lu[5] << 16), lu[6] | (lu[7] << 16));
    *hi = *(bf16x8*)&H;
    *lo = *(bf16x8*)&L;
}

// ---------------- CSR build ----------------

__global__ void k_hist(const int* __restrict__ dst, int* __restrict__ deg) {
    int e = blockIdx.x * 256 + threadIdx.x;
    if (e < N_EDGES) atomicAdd(&deg[dst[e]], 1);
}

__global__ void k_scan(const int* __restrict__ deg, float* __restrict__ dinv,
                       int* __restrict__ offs, int* __restrict__ cursor,
                       int* __restrict__ counter) {
    int lane = threadIdx.x;           // block = 64
    int i = blockIdx.x * 64 + lane;
    int v = (i < N_NODES) ? deg[i] : 0;
    if (i < N_NODES) dinv[i] = rsqrtf((float)(v + 1));   // +1 self loop
    int incl = v;
    #pragma unroll
    for (int d = 1; d < 64; d <<= 1) {
        int t = __shfl_up(incl, d);
        if (lane >= d) incl += t;
    }
    int total = __shfl(incl, 63);
    int base = 0;
    if (lane == 63) base = atomicAdd(counter, total);
    base = __shfl(base, 63);
    int off = base + incl - v;
    if (i < N_NODES) { offs[i] = off; cursor[i] = off; }
}

__global__ void k_scatter(const int* __restrict__ src, const int* __restrict__ dst,
                          int* __restrict__ cursor, int* __restrict__ csr) {
    int e = blockIdx.x * 256 + threadIdx.x;
    if (e < N_EDGES) {
        int d = dst[e];
        int slot = atomicAdd(&cursor[d], 1);
        csr[slot] = src[e];
    }
}

// ---------------- W1 split + transpose: W[512][256] -> hT/lT [256][512] bf16 ----
__global__ void k_splitW(const float* __restrict__ W, unsigned short* __restrict__ hT,
                         unsigned short* __restrict__ lT) {
    int idx = blockIdx.x * 256 + threadIdx.x;   // 131072 total
    int k = idx >> 8;
    int n = idx & 255;
    float v = W[idx];
    unsigned int h = f2bf(v);
    float hf = __uint_as_float(h << 16);
    unsigned int l = f2bf(v - hf);
    hT[n * 512 + k] = (unsigned short)h;
    lT[n * 512 + k] = (unsigned short)l;
}

// ---------------- W2 transpose+bf16: W2[256][64] -> W2T[64][256] bf16 ----------
__global__ void k_prepW2(const float* __restrict__ W, unsigned short* __restrict__ T) {
    int idx = blockIdx.x * 256 + threadIdx.x;   // 16384 total
    int k = idx >> 6;
    int n = idx & 63;
    T[n * 256 + k] = (unsigned short)f2bf(W[idx]);
}

// ---------------- GEMM1: xw1[M][256](bf16) = A[M][512](f32) @ W1 ----------------
// LDS-free streaming: 4 waves/block = 128x128 tile (64x64 quadrants). Fragments
// loaded straight from global (A lines L1-shared by row-waves; B-split L2-hot).
// In-register fp32->hi/lo split; no barriers. XCD-chunked bijective swizzle keeps
// the two column-tiles of a row-stripe on one XCD (A lines shared in its L2).
__global__ __launch_bounds__(256) void k_gemm1_stream(const float* __restrict__ A,
        const unsigned short* __restrict__ BhT, const unsigned short* __restrict__ BlT,
        unsigned short* __restrict__ C, int M) {
    // nwg = 782 = 8*97+6 -> bijective chunk map (m204)
    const int q = 97, r = 6;
    int hw = blockIdx.x;
    int xcd = hw & 7, within = hw >> 3;
    int lt = (xcd < r ? xcd * (q + 1) : r * (q + 1) + (xcd - r) * q) + within;
    const int stripe = lt >> 1;
    const int ch = lt & 1;

    const int tid = threadIdx.x;
    const int lane = tid & 63;
    const int wave = tid >> 6;
    const int rb = stripe * 128 + (wave >> 1) * 64;
    const int cb = ch * 128 + (wave & 1) * 64;
    const int l15 = lane & 15;
    const int g = lane >> 4;

    f32x4 acc[4][4];
    #pragma unroll
    for (int i = 0; i < 4; ++i)
        #pragma unroll
        for (int j = 0; j < 4; ++j) acc[i][j] = (f32x4)0.f;

    // per-lane fragment base pointers
    const unsigned short* bh = BhT + (size_t)(cb + l15) * D_IN + g * 8;
    const unsigned short* bl = BlT + (size_t)(cb + l15) * D_IN + g * 8;
    const float* ap[4];
    #pragma unroll
    for (int i = 0; i < 4; ++i) {
        int row = rb + i * 16 + l15;
        row = row < M ? row : M - 1;           // clamp (stores are guarded)
        ap[i] = A + (size_t)row * D_IN + g * 8;
    }

    for (int k0 = 0; k0 < D_IN; k0 += 32) {
        bf16x8 bhf[4], blf[4];
        #pragma unroll
        for (int j = 0; j < 4; ++j) {
            bhf[j] = *(const bf16x8*)(bh + (size_t)j * 16 * D_IN + k0);
            blf[j] = *(const bf16x8*)(bl + (size_t)j * 16 * D_IN + k0);
        }
        // load all A fragments first (independent loads in flight), then convert+MFMA
        float4 af0[4], af1[4];
        #pragma unroll
        for (int i = 0; i < 4; ++i) {
            af0[i] = *(const float4*)(ap[i] + k0);
            af1[i] = *(const float4*)(ap[i] + k0 + 4);
        }
        #pragma unroll
        for (int i = 0; i < 4; ++i) {
            bf16x8 ahf, alf;
            cvt8(af0[i], af1[i], &ahf, &alf);
            #pragma unroll
            for (int j = 0; j < 4; ++j) {
                acc[i][j] = __builtin_amdgcn_mfma_f32_16x16x32_bf16(ahf, bhf[j], acc[i][j], 0, 0, 0);
                acc[i][j] = __builtin_amdgcn_mfma_f32_16x16x32_bf16(ahf, blf[j], acc[i][j], 0, 0, 0);
                acc[i][j] = __builtin_amdgcn_mfma_f32_16x16x32_bf16(alf, bhf[j], acc[i][j], 0, 0, 0);
            }
        }
    }

    // epilogue -> bf16; C/D layout col=lane&15, row=(lane>>4)*4+reg
    const int crow0 = rb + (lane >> 4) * 4;
    const int ccol = cb + l15;
    #pragma unroll
    for (int i = 0; i < 4; ++i) {
        #pragma unroll
        for (int j = 0; j < 4; ++j) {
            #pragma unroll
            for (int rr = 0; rr < 4; ++rr) {
                int m = crow0 + i * 16 + rr;
                if (m < M) C[(size_t)m * D_HID + ccol + j * 16] = (unsigned short)f2bf(acc[i][j][rr]);
            }
        }
    }
}

// ---------------- layer-1 aggregation (bf16 in / bf16 out), 4-deep unroll ------
__global__ __launch_bounds__(128) void k_agg1(const unsigned int* __restrict__ xw,
                                              const float* __restrict__ dinv,
                                              const int* __restrict__ offs,
                                              const int* __restrict__ degin,
                                              const int* __restrict__ csr,
                                              const float* __restrict__ b1,
                                              unsigned int* __restrict__ h1) {
    const int n = blockIdx.x;
    const int t = threadIdx.x;
    const float dn = dinv[n];
    unsigned int sv = xw[(size_t)n * 128 + t];
    float a0 = dn * bf2f(sv & 0xFFFFu ? (sv << 16) >> 16 : 0);  // placeholder; real below
    a0 = dn * __uint_as_float(sv << 16);
    float a1 = dn * __uint_as_float(sv & 0xFFFF0000u);
    const int start = offs[n];
    const int cnt = degin[n];
    int i = 0;
    for (; i + 4 <= cnt; i += 4) {
        int s0 = csr[start + i];
        int s1 = csr[start + i + 1];
        int s2 = csr[start + i + 2];
        int s3 = csr[start + i + 3];
        float w0 = dinv[s0], w1 = dinv[s1], w2 = dinv[s2], w3 = dinv[s3];
        unsigned int v0 = xw[(size_t)s0 * 128 + t];
        unsigned int v1 = xw[(size_t)s1 * 128 + t];
        unsigned int v2 = xw[(size_t)s2 * 128 + t];
        unsigned int v3 = xw[(size_t)s3 * 128 + t];
        a0 = fmaf(w0, __uint_as_float(v0 << 16), a0);
        a1 = fmaf(w0, __uint_as_float(v0 & 0xFFFF0000u), a1);
        a0 = fmaf(w1, __uint_as_float(v1 << 16), a0);
        a1 = fmaf(w1, __uint_as_float(v1 & 0xFFFF0000u), a1);
        a0 = fmaf(w2, __uint_as_float(v2 << 16), a0);
        a1 = fmaf(w2, __uint_as_float(v2 & 0xFFFF0000u), a1);
        a0 = fmaf(w3, __uint_as_float(v3 << 16), a0);
        a1 = fmaf(w3, __uint_as_float(v3 & 0xFFFF0000u), a1);
    }
    for (; i < cnt; ++i) {
        int s0 = csr[start + i];
        float w0 = dinv[s0];
        unsigned int v0 = xw[(size_t)s0 * 128 + t];
        a0 = fmaf(w0, __uint_as_float(v0 << 16), a0);
        a1 = fmaf(w0, __uint_as_float(v0 & 0xFFFF0000u), a1);
    }
    float o0 = fmaxf(fmaf(a0, dn, b1[2 * t]), 0.f);
    float o1 = fmaxf(fmaf(a1, dn, b1[2 * t + 1]), 0.f);
    h1[(size_t)n * 128 + t] = f2bf(o0) | (f2bf(o1) << 16);
}

// ---------------- GEMM2: hw2[M][64](bf16) = h1[M][256](bf16) @ W2 ---------------
// LDS-free streaming: one wave per 64-row stripe, full 64-col output.
__global__ __launch_bounds__(256) void k_gemm2_stream(const unsigned short* __restrict__ A,
        const unsigned short* __restrict__ BT, unsigned short* __restrict__ C, int M) {
    const int gw = (blockIdx.x * 256 + threadIdx.x) >> 6;   // global wave id
    if (gw >= 782) return;                                  // 782*64 = 50048 rows
    const int lane = threadIdx.x & 63;
    const int l15 = lane & 15;
    const int g = lane >> 4;
    const int rb = gw * 64;

    f32x4 acc[4][4];
    #pragma unroll
    for (int i = 0; i < 4; ++i)
        #pragma unroll
        for (int j = 0; j < 4; ++j) acc[i][j] = (f32x4)0.f;

    const unsigned short* bt = BT + (size_t)l15 * D_HID + g * 8;
    const unsigned short* ap[4];
    #pragma unroll
    for (int i = 0; i < 4; ++i) {
        int row = rb + i * 16 + l15;
        row = row < M ? row : M - 1;
        ap[i] = A + (size_t)row * D_HID + g * 8;
    }

    for (int k0 = 0; k0 < D_HID; k0 += 32) {
        bf16x8 bf[4];
        #pragma unroll
        for (int j = 0; j < 4; ++j)
            bf[j] = *(const bf16x8*)(bt + (size_t)j * 16 * D_HID + k0);
        #pragma unroll
        for (int i = 0; i < 4; ++i) {
            bf16x8 af = *(const bf16x8*)(ap[i] + k0);
            #pragma unroll
            for (int j = 0; j < 4; ++j)
                acc[i][j] = __builtin_amdgcn_mfma_f32_16x16x32_bf16(af, bf[j], acc[i][j], 0, 0, 0);
        }
    }

    const int crow0 = rb + (lane >> 4) * 4;
    #pragma unroll
    for (int i = 0; i < 4; ++i) {
        #pragma unroll
        for (int j = 0; j < 4; ++j) {
            #pragma unroll
            for (int rr = 0; rr < 4; ++rr) {
                int m = crow0 + i * 16 + rr;
                if (m < M) C[(size_t)m * D_OUT + l15 + j * 16] = (unsigned short)f2bf(acc[i][j][rr]);
            }
        }
    }
}

// ---------------- layer-2 aggregation + softmax (bf16 gather), 4-deep unroll ----
__global__ __launch_bounds__(256) void k_agg2(const unsigned short* __restrict__ hw,
                                              const float* __restrict__ dinv,
                                              const int* __restrict__ offs,
                                              const int* __restrict__ degin,
                                              const int* __restrict__ csr,
                                              const float* __restrict__ b2,
                                              float* __restrict__ out) {
    const int wave = threadIdx.x >> 6;
    const int lane = threadIdx.x & 63;
    const int n = blockIdx.x * 4 + wave;   // 50000 = 12500*4
    const float dn = dinv[n];
    float acc = dn * bf2f(hw[(size_t)n * D_OUT + lane]);
    const int start = offs[n];
    const int cnt = degin[n];
    int i = 0;
    for (; i + 4 <= cnt; i += 4) {
        int s0 = csr[start + i];
        int s1 = csr[start + i + 1];
        int s2 = csr[start + i + 2];
        int s3 = csr[start + i + 3];
        float w0 = dinv[s0], w1 = dinv[s1], w2 = dinv[s2], w3 = dinv[s3];
        float v0 = bf2f(hw[(size_t)s0 * D_OUT + lane]);
        float v1 = bf2f(hw[(size_t)s1 * D_OUT + lane]);
        float v2 = bf2f(hw[(size_t)s2 * D_OUT + lane]);
        float v3 = bf2f(hw[(size_t)s3 * D_OUT + lane]);
        acc = fmaf(w0, v0, acc);
        acc = fmaf(w1, v1, acc);
        acc = fmaf(w2, v2, acc);
        acc = fmaf(w3, v3, acc);
    }
    for (; i < cnt; ++i) {
        int s0 = csr[start + i];
        acc = fmaf(dinv[s0], bf2f(hw[(size_t)s0 * D_OUT + lane]), acc);
    }
    float logit = fmaf(acc, dn, b2[lane]);
    float m = logit;
    #pragma unroll
    for (int d = 32; d > 0; d >>= 1) m = fmaxf(m, __shfl_xor(m, d));
    float e = expf(logit - m);
    float ssum = e;
    #pragma unroll
    for (int d = 32; d > 0; d >>= 1) ssum += __shfl_xor(ssum, d);
    out[(size_t)n * D_OUT + lane] = e / ssum;
}

// ---------------- launch ----------------

extern "C" void kernel_launch(void* const* d_in, const int* in_sizes, int n_in,
                              void* d_out, int out_size, void* d_ws, size_t ws_size,
                              hipStream_t stream) {
    const float* x  = (const float*)d_in[0];
    const int*   ei = (const int*)d_in[1];
    const float* W1 = (const float*)d_in[2];
    const float* b1 = (const float*)d_in[3];
    const float* W2 = (const float*)d_in[4];
    const float* b2 = (const float*)d_in[5];
    float* out = (float*)d_out;

    const int* src = ei;
    const int* dst = ei + N_EDGES;

    char* ws = (char*)d_ws;
    int*   counter = (int*)(ws + OFF_COUNTER);
    int*   deg     = (int*)(ws + OFF_DEG);
    float* dinv    = (float*)(ws + OFF_DINV);
    int*   offs    = (int*)(ws + OFF_OFFS);
    int*   cursor  = (int*)(ws + OFF_CURSOR);
    int*   csr     = (int*)(ws + OFF_CSR);
    unsigned short* xw1b = (unsigned short*)(ws + OFF_XW1);   // bf16 [N][256]
    unsigned short* h1b  = (unsigned short*)(ws + OFF_H1);    // bf16 [N][256]
    unsigned short* hw2b = (unsigned short*)(ws + OFF_XW1);   // bf16 [N][64], aliases xw1b
    unsigned short* BhT = (unsigned short*)(ws + OFF_BHT);
    unsigned short* BlT = (unsigned short*)(ws + OFF_BLT);
    unsigned short* W2T = (unsigned short*)(ws + OFF_W2T);

    hipMemsetAsync(ws, 0, OFF_DEG + N_NODES * sizeof(int), stream);

    k_hist<<<(N_EDGES + 255) / 256, 256, 0, stream>>>(dst, deg);
    k_scan<<<(N_NODES + 63) / 64, 64, 0, stream>>>(deg, dinv, offs, cursor, counter);
    k_scatter<<<(N_EDGES + 255) / 256, 256, 0, stream>>>(src, dst, cursor, csr);

    k_splitW<<<512, 256, 0, stream>>>(W1, BhT, BlT);
    k_prepW2<<<64, 256, 0, stream>>>(W2, W2T);

    k_gemm1_stream<<<782, 256, 0, stream>>>(x, BhT, BlT, xw1b, N_NODES);
    k_agg1<<<N_NODES, 128, 0, stream>>>((const unsigned int*)xw1b, dinv, offs, deg, csr, b1, (unsigned int*)h1b);
    k_gemm2_stream<<<196, 256, 0, stream>>>(h1b, W2T, hw2b, N_NODES);
    k_agg2<<<N_NODES / 4, 256, 0, stream>>>(hw2b, dinv, offs, deg, csr, b2, out);
}

// Round 7
// 396.001 us; speedup vs baseline: 1.1836x; 1.1836x over previous
//
#include <hip/hip_runtime.h>
#include <hip/hip_bf16.h>
#include <math.h>

// ---------------------------------------------------------------------------
// 2-layer GCN on MI355X.
//   CSR build (hist -> wave-scan -> scatter)
//   xw1 = x @ W1    LDS MFMA GEMM, T14 prefetch: bf16(A) * (W1hi + W1lo), OUT=bf16
//   h1  = relu(sym-norm-agg(xw1) + b1)   bf16 gather, 4-deep unroll
//   hw2 = h1 @ W2   LDS MFMA (W2 resident), OUT=bf16
//   out = softmax(sym-norm-agg(hw2) + b2)  bf16 gather
// ---------------------------------------------------------------------------

#define N_NODES 50000
#define N_EDGES 800000
#define D_IN    512
#define D_HID   256
#define D_OUT   64

#define OFF_COUNTER 0
#define OFF_DEG     256
#define OFF_DINV    (OFF_DEG + 200704)
#define OFF_OFFS    (OFF_DINV + 200704)
#define OFF_CURSOR  (OFF_OFFS + 200704)
#define OFF_CSR     (OFF_CURSOR + 200704)
#define OFF_XW1     (OFF_CSR + 3200000)     // xw1 bf16 25.6MB; later hw2 bf16 6.4MB
#define OFF_H1      (OFF_XW1 + 51200000)    // h1 bf16 25.6MB
// W1 hi/lo split inside the h1 region (dead before agg1 writes h1)
#define OFF_BHT     OFF_H1
#define OFF_BLT     (OFF_H1 + 524288)
#define OFF_W2T     (OFF_H1 + 25600000)     // W2T bf16 32KB
// total ~105 MB

typedef __attribute__((ext_vector_type(8))) short bf16x8;
typedef __attribute__((ext_vector_type(4))) float f32x4;

// round-to-nearest-even fp32 -> bf16 bits
__device__ __forceinline__ unsigned int f2bf(float v) {
    unsigned int u = __float_as_uint(v);
    return (u + 0x7FFFu + ((u >> 16) & 1u)) >> 16;
}
__device__ __forceinline__ float bf2f(unsigned int b) { return __uint_as_float(b << 16); }

// ---------------- CSR build ----------------

__global__ void k_hist(const int* __restrict__ dst, int* __restrict__ deg) {
    int e = blockIdx.x * 256 + threadIdx.x;
    if (e < N_EDGES) atomicAdd(&deg[dst[e]], 1);
}

__global__ void k_scan(const int* __restrict__ deg, float* __restrict__ dinv,
                       int* __restrict__ offs, int* __restrict__ cursor,
                       int* __restrict__ counter) {
    int lane = threadIdx.x;           // block = 64
    int i = blockIdx.x * 64 + lane;
    int v = (i < N_NODES) ? deg[i] : 0;
    if (i < N_NODES) dinv[i] = rsqrtf((float)(v + 1));   // +1 self loop
    int incl = v;
    #pragma unroll
    for (int d = 1; d < 64; d <<= 1) {
        int t = __shfl_up(incl, d);
        if (lane >= d) incl += t;
    }
    int total = __shfl(incl, 63);
    int base = 0;
    if (lane == 63) base = atomicAdd(counter, total);
    base = __shfl(base, 63);
    int off = base + incl - v;
    if (i < N_NODES) { offs[i] = off; cursor[i] = off; }
}

__global__ void k_scatter(const int* __restrict__ src, const int* __restrict__ dst,
                          int* __restrict__ cursor, int* __restrict__ csr) {
    int e = blockIdx.x * 256 + threadIdx.x;
    if (e < N_EDGES) {
        int d = dst[e];
        int slot = atomicAdd(&cursor[d], 1);
        csr[slot] = src[e];
    }
}

// ---------------- weight prep (merged): W1 split+T, W2 bf16+T ----------------
__global__ void k_prep(const float* __restrict__ W1, const float* __restrict__ W2,
                       unsigned short* __restrict__ hT, unsigned short* __restrict__ lT,
                       unsigned short* __restrict__ W2T) {
    int b = blockIdx.x;
    if (b < 512) {                        // W1[512][256] -> hT/lT [256][512]
        int idx = b * 256 + threadIdx.x;
        int k = idx >> 8, n = idx & 255;
        float v = W1[idx];
        unsigned int h = f2bf(v);
        float hf = __uint_as_float(h << 16);
        unsigned int l = f2bf(v - hf);
        hT[n * 512 + k] = (unsigned short)h;
        lT[n * 512 + k] = (unsigned short)l;
    } else {                              // W2[256][64] -> W2T[64][256]
        int idx = (b - 512) * 256 + threadIdx.x;
        int k = idx >> 6, n = idx & 63;
        W2T[n * 256 + k] = (unsigned short)f2bf(W2[idx]);
    }
}

// ---------------- GEMM1: xw1[M][256](bf16) = bf16(A[M][512]) @ (W1h+W1l) -------
// 128x128 tile, 4 waves (64x64 quadrants), BK=32, 16 K-steps.
// T14: global loads for step t+1 issued BEFORE ds_read+MFMA of step t;
// convert+LDS-write after the read barrier. Single-buffered LDS, pad 40.
__global__ __launch_bounds__(256) void k_gemm1_mfma(const float* __restrict__ A,
        const unsigned short* __restrict__ BhT, const unsigned short* __restrict__ BlT,
        unsigned short* __restrict__ C, int M) {
    __shared__ unsigned short Ab[128][40];
    __shared__ unsigned short Bh[128][40];   // [col][k]
    __shared__ unsigned short Bl[128][40];

    const int tid = threadIdx.x;
    const int lane = tid & 63;
    const int wave = tid >> 6;
    const int wrow = (wave >> 1) * 64;
    const int wcol = (wave & 1) * 64;
    const int rowBase = blockIdx.x * 128;
    const int colBase = blockIdx.y * 128;

    // staging assignment: thread -> (row/col, k-half of 16)
    const int arow = tid >> 1;
    const int ahalf = tid & 1;
    const int grow = rowBase + arow;
    const bool aval = (grow < M);
    const float* aptr = A + (size_t)grow * D_IN + ahalf * 16;
    const unsigned short* bhptr = BhT + (size_t)(colBase + arow) * D_IN + ahalf * 16;
    const unsigned short* blptr = BlT + (size_t)(colBase + arow) * D_IN + ahalf * 16;

    f32x4 acc[4][4];
    #pragma unroll
    for (int i = 0; i < 4; ++i)
        #pragma unroll
        for (int j = 0; j < 4; ++j) acc[i][j] = (f32x4)0.f;

    const int l15 = lane & 15;
    const int g = lane >> 4;

    float4 av0, av1, av2, av3;
    uint4 bh0, bh1, bl0, bl1;

    // ---- staging load (to regs) ----
    auto LOADS = [&](int k0) {
        av0 = av1 = av2 = av3 = make_float4(0.f, 0.f, 0.f, 0.f);
        if (aval) {
            av0 = *(const float4*)(aptr + k0);
            av1 = *(const float4*)(aptr + k0 + 4);
            av2 = *(const float4*)(aptr + k0 + 8);
            av3 = *(const float4*)(aptr + k0 + 12);
        }
        bh0 = *(const uint4*)(bhptr + k0);
        bh1 = *(const uint4*)(bhptr + k0 + 8);
        bl0 = *(const uint4*)(blptr + k0);
        bl1 = *(const uint4*)(blptr + k0 + 8);
    };
    // ---- convert + LDS write ----
    auto STORE = [&]() {
        float vv[16] = {av0.x,av0.y,av0.z,av0.w, av1.x,av1.y,av1.z,av1.w,
                        av2.x,av2.y,av2.z,av2.w, av3.x,av3.y,av3.z,av3.w};
        unsigned int p[8];
        #pragma unroll
        for (int e = 0; e < 8; ++e)
            p[e] = f2bf(vv[2*e]) | (f2bf(vv[2*e+1]) << 16);
        *(uint4*)&Ab[arow][ahalf*16]     = make_uint4(p[0], p[1], p[2], p[3]);
        *(uint4*)&Ab[arow][ahalf*16 + 8] = make_uint4(p[4], p[5], p[6], p[7]);
        *(uint4*)&Bh[arow][ahalf*16]     = bh0;
        *(uint4*)&Bh[arow][ahalf*16 + 8] = bh1;
        *(uint4*)&Bl[arow][ahalf*16]     = bl0;
        *(uint4*)&Bl[arow][ahalf*16 + 8] = bl1;
    };

    // prologue: stage k0 = 0
    LOADS(0);
    STORE();
    __syncthreads();

    for (int k0 = 0; k0 < D_IN; k0 += 32) {
        const int kn = k0 + 32;
        if (kn < D_IN) LOADS(kn);          // in flight during MFMA phase

        bf16x8 bhf[4], blf[4];
        #pragma unroll
        for (int j = 0; j < 4; ++j) {
            bhf[j] = *(const bf16x8*)&Bh[wcol + j*16 + l15][g*8];
            blf[j] = *(const bf16x8*)&Bl[wcol + j*16 + l15][g*8];
        }
        #pragma unroll
        for (int i = 0; i < 4; ++i) {
            bf16x8 abf = *(const bf16x8*)&Ab[wrow + i*16 + l15][g*8];
            #pragma unroll
            for (int j = 0; j < 4; ++j) {
                acc[i][j] = __builtin_amdgcn_mfma_f32_16x16x32_bf16(abf, bhf[j], acc[i][j], 0, 0, 0);
                acc[i][j] = __builtin_amdgcn_mfma_f32_16x16x32_bf16(abf, blf[j], acc[i][j], 0, 0, 0);
            }
        }
        __syncthreads();                   // all reads of current tile done
        if (kn < D_IN) {
            STORE();
            __syncthreads();               // next tile visible
        }
    }

    // epilogue -> bf16; C/D layout col=lane&15, row=(lane>>4)*4+reg
    const int crow0 = rowBase + wrow + (lane >> 4) * 4;
    const int ccol = colBase + wcol + l15;
    #pragma unroll
    for (int i = 0; i < 4; ++i) {
        #pragma unroll
        for (int j = 0; j < 4; ++j) {
            #pragma unroll
            for (int r = 0; r < 4; ++r) {
                int m = crow0 + i * 16 + r;
                if (m < M) C[(size_t)m * D_HID + ccol + j * 16] = (unsigned short)f2bf(acc[i][j][r]);
            }
        }
    }
}

// ---------------- layer-1 aggregation (bf16 in / bf16 out), 4-deep unroll ------
__global__ __launch_bounds__(128) void k_agg1(const unsigned int* __restrict__ xw,
                                              const float* __restrict__ dinv,
                                              const int* __restrict__ offs,
                                              const int* __restrict__ degin,
                                              const int* __restrict__ csr,
                                              const float* __restrict__ b1,
                                              unsigned int* __restrict__ h1) {
    const int n = blockIdx.x;
    const int t = threadIdx.x;
    const float dn = dinv[n];
    unsigned int sv = xw[(size_t)n * 128 + t];
    float a0 = dn * __uint_as_float(sv << 16);
    float a1 = dn * __uint_as_float(sv & 0xFFFF0000u);
    const int start = offs[n];
    const int cnt = degin[n];
    int i = 0;
    for (; i + 4 <= cnt; i += 4) {
        int s0 = csr[start + i];
        int s1 = csr[start + i + 1];
        int s2 = csr[start + i + 2];
        int s3 = csr[start + i + 3];
        float w0 = dinv[s0], w1 = dinv[s1], w2 = dinv[s2], w3 = dinv[s3];
        unsigned int v0 = xw[(size_t)s0 * 128 + t];
        unsigned int v1 = xw[(size_t)s1 * 128 + t];
        unsigned int v2 = xw[(size_t)s2 * 128 + t];
        unsigned int v3 = xw[(size_t)s3 * 128 + t];
        a0 = fmaf(w0, __uint_as_float(v0 << 16), a0);
        a1 = fmaf(w0, __uint_as_float(v0 & 0xFFFF0000u), a1);
        a0 = fmaf(w1, __uint_as_float(v1 << 16), a0);
        a1 = fmaf(w1, __uint_as_float(v1 & 0xFFFF0000u), a1);
        a0 = fmaf(w2, __uint_as_float(v2 << 16), a0);
        a1 = fmaf(w2, __uint_as_float(v2 & 0xFFFF0000u), a1);
        a0 = fmaf(w3, __uint_as_float(v3 << 16), a0);
        a1 = fmaf(w3, __uint_as_float(v3 & 0xFFFF0000u), a1);
    }
    for (; i < cnt; ++i) {
        int s0 = csr[start + i];
        float w0 = dinv[s0];
        unsigned int v0 = xw[(size_t)s0 * 128 + t];
        a0 = fmaf(w0, __uint_as_float(v0 << 16), a0);
        a1 = fmaf(w0, __uint_as_float(v0 & 0xFFFF0000u), a1);
    }
    float o0 = fmaxf(fmaf(a0, dn, b1[2 * t]), 0.f);
    float o1 = fmaxf(fmaf(a1, dn, b1[2 * t + 1]), 0.f);
    h1[(size_t)n * 128 + t] = f2bf(o0) | (f2bf(o1) << 16);
}

// ---------------- GEMM2: hw2[M][64](bf16) = h1[M][256](bf16) @ W2 ---------------
// 128-row tile, 4 waves x 32 rows, W2T resident in LDS, BK=32, 8 K-steps.
__global__ __launch_bounds__(256) void k_gemm2_mfma(const unsigned short* __restrict__ A,
        const unsigned short* __restrict__ BT, unsigned short* __restrict__ C, int M) {
    __shared__ unsigned short As[128][40];
    __shared__ unsigned short Bs[64][260];   // [col][k]

    const int tid = threadIdx.x;
    const int lane = tid & 63;
    const int wave = tid >> 6;
    const int wrow = wave * 32;
    const int rowBase = blockIdx.x * 128;

    // load entire W2T (16384 shorts) once
    {
        const int col = tid >> 2;
        const int kq = (tid & 3) * 64;
        const unsigned short* p = BT + (size_t)col * 256 + kq;
        #pragma unroll
        for (int u = 0; u < 8; ++u) {
            uint4 v = *(const uint4*)(p + u * 8);
            *(uint4*)&Bs[col][kq + u * 8] = v;
        }
    }

    const int arow = tid >> 1;
    const int ahalf = tid & 1;
    const int grow = rowBase + arow;
    const bool aval = (grow < M);
    const unsigned short* aptr = A + (size_t)grow * D_HID + ahalf * 16;

    f32x4 acc[2][4];
    #pragma unroll
    for (int i = 0; i < 2; ++i)
        #pragma unroll
        for (int j = 0; j < 4; ++j) acc[i][j] = (f32x4)0.f;

    const int l15 = lane & 15;
    const int g = lane >> 4;

    uint4 a0, a1;
    auto LOADS = [&](int k0) {
        a0 = a1 = make_uint4(0, 0, 0, 0);
        if (aval) {
            a0 = *(const uint4*)(aptr + k0);
            a1 = *(const uint4*)(aptr + k0 + 8);
        }
    };

    LOADS(0);
    *(uint4*)&As[arow][ahalf*16]     = a0;
    *(uint4*)&As[arow][ahalf*16 + 8] = a1;
    __syncthreads();   // As(0) + Bs ready

    for (int k0 = 0; k0 < D_HID; k0 += 32) {
        const int kn = k0 + 32;
        if (kn < D_HID) LOADS(kn);

        bf16x8 bf[4];
        #pragma unroll
        for (int j = 0; j < 4; ++j)
            bf[j] = *(const bf16x8*)&Bs[j*16 + l15][k0 + g*8];
        #pragma unroll
        for (int i = 0; i < 2; ++i) {
            bf16x8 af = *(const bf16x8*)&As[wrow + i*16 + l15][g*8];
            #pragma unroll
            for (int j = 0; j < 4; ++j)
                acc[i][j] = __builtin_amdgcn_mfma_f32_16x16x32_bf16(af, bf[j], acc[i][j], 0, 0, 0);
        }
        __syncthreads();
        if (kn < D_HID) {
            *(uint4*)&As[arow][ahalf*16]     = a0;
            *(uint4*)&As[arow][ahalf*16 + 8] = a1;
            __syncthreads();
        }
    }

    const int crow0 = rowBase + wrow + (lane >> 4) * 4;
    #pragma unroll
    for (int i = 0; i < 2; ++i) {
        #pragma unroll
        for (int j = 0; j < 4; ++j) {
            #pragma unroll
            for (int r = 0; r < 4; ++r) {
                int m = crow0 + i * 16 + r;
                if (m < M) C[(size_t)m * D_OUT + l15 + j * 16] = (unsigned short)f2bf(acc[i][j][r]);
            }
        }
    }
}

// ---------------- layer-2 aggregation + softmax (bf16 gather) ----------------
__global__ __launch_bounds__(256) void k_agg2(const unsigned short* __restrict__ hw,
                                              const float* __restrict__ dinv,
                                              const int* __restrict__ offs,
                                              const int* __restrict__ degin,
                                              const int* __restrict__ csr,
                                              const float* __restrict__ b2,
                                              float* __restrict__ out) {
    const int wave = threadIdx.x >> 6;
    const int lane = threadIdx.x & 63;
    const int n = blockIdx.x * 4 + wave;   // 50000 = 12500*4
    const float dn = dinv[n];
    float acc = dn * bf2f(hw[(size_t)n * D_OUT + lane]);
    const int start = offs[n];
    const int cnt = degin[n];
    int i = 0;
    for (; i + 4 <= cnt; i += 4) {
        int s0 = csr[start + i];
        int s1 = csr[start + i + 1];
        int s2 = csr[start + i + 2];
        int s3 = csr[start + i + 3];
        float w0 = dinv[s0], w1 = dinv[s1], w2 = dinv[s2], w3 = dinv[s3];
        float v0 = bf2f(hw[(size_t)s0 * D_OUT + lane]);
        float v1 = bf2f(hw[(size_t)s1 * D_OUT + lane]);
        float v2 = bf2f(hw[(size_t)s2 * D_OUT + lane]);
        float v3 = bf2f(hw[(size_t)s3 * D_OUT + lane]);
        acc = fmaf(w0, v0, acc);
        acc = fmaf(w1, v1, acc);
        acc = fmaf(w2, v2, acc);
        acc = fmaf(w3, v3, acc);
    }
    for (; i < cnt; ++i) {
        int s0 = csr[start + i];
        acc = fmaf(dinv[s0], bf2f(hw[(size_t)s0 * D_OUT + lane]), acc);
    }
    float logit = fmaf(acc, dn, b2[lane]);
    float m = logit;
    #pragma unroll
    for (int d = 32; d > 0; d >>= 1) m = fmaxf(m, __shfl_xor(m, d));
    float e = expf(logit - m);
    float ssum = e;
    #pragma unroll
    for (int d = 32; d > 0; d >>= 1) ssum += __shfl_xor(ssum, d);
    out[(size_t)n * D_OUT + lane] = e / ssum;
}

// ---------------- launch ----------------

extern "C" void kernel_launch(void* const* d_in, const int* in_sizes, int n_in,
                              void* d_out, int out_size, void* d_ws, size_t ws_size,
                              hipStream_t stream) {
    const float* x  = (const float*)d_in[0];
    const int*   ei = (const int*)d_in[1];
    const float* W1 = (const float*)d_in[2];
    const float* b1 = (const float*)d_in[3];
    const float* W2 = (const float*)d_in[4];
    const float* b2 = (const float*)d_in[5];
    float* out = (float*)d_out;

    const int* src = ei;
    const int* dst = ei + N_EDGES;

    char* ws = (char*)d_ws;
    int*   counter = (int*)(ws + OFF_COUNTER);
    int*   deg     = (int*)(ws + OFF_DEG);
    float* dinv    = (float*)(ws + OFF_DINV);
    int*   offs    = (int*)(ws + OFF_OFFS);
    int*   cursor  = (int*)(ws + OFF_CURSOR);
    int*   csr     = (int*)(ws + OFF_CSR);
    unsigned short* xw1b = (unsigned short*)(ws + OFF_XW1);   // bf16 [N][256]
    unsigned short* h1b  = (unsigned short*)(ws + OFF_H1);    // bf16 [N][256]
    unsigned short* hw2b = (unsigned short*)(ws + OFF_XW1);   // bf16 [N][64], aliases xw1b
    unsigned short* BhT = (unsigned short*)(ws + OFF_BHT);
    unsigned short* BlT = (unsigned short*)(ws + OFF_BLT);
    unsigned short* W2T = (unsigned short*)(ws + OFF_W2T);

    hipMemsetAsync(ws, 0, OFF_DEG + N_NODES * sizeof(int), stream);

    k_hist<<<(N_EDGES + 255) / 256, 256, 0, stream>>>(dst, deg);
    k_scan<<<(N_NODES + 63) / 64, 64, 0, stream>>>(deg, dinv, offs, cursor, counter);
    k_scatter<<<(N_EDGES + 255) / 256, 256, 0, stream>>>(src, dst, cursor, csr);

    k_prep<<<576, 256, 0, stream>>>(W1, W2, BhT, BlT, W2T);

    k_gemm1_mfma<<<dim3((N_NODES + 127) / 128, D_HID / 128), 256, 0, stream>>>(x, BhT, BlT, xw1b, N_NODES);
    k_agg1<<<N_NODES, 128, 0, stream>>>((const unsigned int*)xw1b, dinv, offs, deg, csr, b1, (unsigned int*)h1b);
    k_gemm2_mfma<<<(N_NODES + 127) / 128, 256, 0, stream>>>(h1b, W2T, hw2b, N_NODES);
    k_agg2<<<N_NODES / 4, 256, 0, stream>>>(hw2b, dinv, offs, deg, csr, b2, out);
}